// Round 18
// baseline (277.563 us; speedup 1.0000x reference)
//
#include <hip/hip_runtime.h>
#include <hip/hip_bf16.h>

// ControllableNCA step. B=64, C=20, H=W=128. LIVING=3, ALIVE_TH=0.1, FIRE_RATE=0.5.
// Pass 1: pre-alive mask (u8, 4 px/thread) + inline w2->bf16 frag prep (blocks 0-1).
// Pass 2: conv(fp32, offset-load neighbors) -> GEMM1 3-term split-bf16
//         (fp32-grade h; w1 hi/lo swizzled LDS) -> ch3 update fp32 on VALU
//         (mask channel: threshold discontinuity) -> GEMM2 single-bf16 ->
//         stochastic update. XCD-swizzled grid; epilogue rnd/x PREFETCHED
//         before GEMM1 (hidden under MFMA).
// Pass 3: post-alive + life mask + clip, 4 px/thread float4.
// R18: R16 chassis (best verified, 250us) + epilogue prefetch + prep merge.
//      R17's 2-thr/px restructure failed (absmax .37, bug unlocated) - reverted.

#define BB 64
#define CC 20
#define HH 128
#define WW 128
#define LIVCH 3
#define NPIX (BB*HH*WW)

typedef __attribute__((ext_vector_type(8))) short short8;
typedef __attribute__((ext_vector_type(4))) float f32x4;

#define LDS_FENCE() asm volatile("" ::: "memory")

static __device__ __forceinline__ unsigned short f2bf(float f) {
    __hip_bfloat16 h = __float2bfloat16(f);   // RNE
    return *reinterpret_cast<unsigned short*>(&h);
}
static __device__ __forceinline__ float bf2f(unsigned short u) {
    union { unsigned int i; float f; } c; c.i = ((unsigned int)u) << 16; return c.f;
}

// ---- Pass 1: pre-alive mask, 4 px/thread; blocks 0-1 also convert w2->w2f ----
__global__ __launch_bounds__(256) void nca_pre_mask(const float* __restrict__ x,
                                                    unsigned char* __restrict__ mpre,
                                                    const float* __restrict__ w2,
                                                    unsigned short* __restrict__ w2f) {
    int t = blockIdx.x * 256 + threadIdx.x;   // NPIX/4 threads
    // inline prep: w2f = 8 frags (ks2*2 + nt2) x 64 lanes x 8 bf16 (n>=20 zero)
    if (t < 512) {
        int f2 = t >> 6, lane = t & 63;
        int ks2 = f2 >> 1, nt2 = f2 & 1;
        int n = nt2 * 16 + (lane & 15), kb = ks2 * 32 + (lane >> 4) * 8;
        short8 o;
        #pragma unroll
        for (int j = 0; j < 8; ++j) {
            float v = (n < CC) ? w2[n * 128 + kb + j] : 0.0f;
            o[j] = (short)f2bf(v);
        }
        *reinterpret_cast<short8*>(w2f + f2 * 512 + lane * 8) = o;
    }
    int base = t << 2;
    int w4 = base & 127;
    int h  = (base >> 7) & 127;
    int b  = base >> 14;
    const float* ch = x + ((size_t)b * CC + LIVCH) * (HH * WW);
    float4 L = {-1e30f, -1e30f, -1e30f, -1e30f};
    float4 Cn = L, R = L;
    #pragma unroll
    for (int dy = -1; dy <= 1; ++dy) {
        int yy = h + dy;
        if ((unsigned)yy < HH) {
            const float* row = ch + yy * WW;
            float4 c4 = *reinterpret_cast<const float4*>(row + w4);
            Cn.x = fmaxf(Cn.x, c4.x); Cn.y = fmaxf(Cn.y, c4.y);
            Cn.z = fmaxf(Cn.z, c4.z); Cn.w = fmaxf(Cn.w, c4.w);
            if (w4 > 0) {
                float4 l4 = *reinterpret_cast<const float4*>(row + w4 - 4);
                L.w = fmaxf(L.w, l4.w);
            }
            if (w4 < 124) {
                float4 r4 = *reinterpret_cast<const float4*>(row + w4 + 4);
                R.x = fmaxf(R.x, r4.x);
            }
        }
    }
    float m0 = fmaxf(fmaxf(L.w,  Cn.x), Cn.y);
    float m1 = fmaxf(fmaxf(Cn.x, Cn.y), Cn.z);
    float m2 = fmaxf(fmaxf(Cn.y, Cn.z), Cn.w);
    float m3 = fmaxf(fmaxf(Cn.z, Cn.w), R.x);
    unsigned int out = (m0 > 0.1f ? 1u : 0u) | (m1 > 0.1f ? 1u << 8 : 0u)
                     | (m2 > 0.1f ? 1u << 16 : 0u) | (m3 > 0.1f ? 1u << 24 : 0u);
    reinterpret_cast<unsigned int*>(mpre)[t] = out;
}

// Block: 512 threads = 8 waves; 512 pixels = 4 image rows. Grid = 64*32 = 2048.
__global__ __launch_bounds__(512, 2) void nca_main_mfma(
    const float* __restrict__ x, const float* __restrict__ goal,
    const float* __restrict__ rnd, const float* __restrict__ pw,
    const float* __restrict__ w1, const float* __restrict__ b1,
    const unsigned short* __restrict__ w2f, const float* __restrict__ w2,
    const unsigned char* __restrict__ mpre,
    float* __restrict__ xnew, float* __restrict__ ch3out) {

    // w1 hi/lo: [128][64] bf16, UNPADDED, 16B-chunk XOR swizzle:
    //   elem (n,k) at short index n*64 + (((k>>3)^(n&7))<<3) + (k&7)
    __shared__ unsigned short w1h[128 * 64];   // 16384 B
    __shared__ unsigned short w1l[128 * 64];   // 16384 B
    // per-wave shared tile: p view [16][68] f32, h view [16][136] bf16
    __shared__ float ph_buf[8][16 * 68];       // 34816 B
    // total 67584 B -> 2 blocks/CU

    const int tid  = threadIdx.x;
    const int lane = tid & 63;
    const int wv   = tid >> 6;                 // 0..7
    // bijective XCD swizzle (nwg=2048, 8 XCDs)
    const int bid  = blockIdx.x;
    const int blk  = ((bid & 7) << 8) + (bid >> 3);
    const int b    = blk >> 5;                 // 32 blocks per image
    const int y0   = (blk & 31) * 4;           // 4 rows per block

    // ---- stage w1 hi/lo split (Dekker: v = hi + lo + O(2^-17 v)), swizzled ----
    for (int i = tid; i < 128 * 64; i += 512) {
        int n = i >> 6, k = i & 63;
        float v = (k < 60) ? w1[n * 60 + k] : 0.0f;
        unsigned short hi = f2bf(v);
        int si = (n << 6) + ((((k >> 3) ^ (n & 7)) << 3)) + (k & 7);
        w1h[si] = hi;
        w1l[si] = f2bf(v - bf2f(hi));
    }
    __syncthreads();   // w1 staging visible to all waves

    // ---- depthwise 3x3 conv on xg, per-lane pixel, fp32, offset-load neighbors ----
    const int y    = y0 + (tid >> 7);          // tid>>7 in 0..3
    const int wcol = tid & 127;
    const int dm   = (wcol > 0)   ? 1 : 0;     // left-neighbor valid
    const int dp   = (wcol < 127) ? 1 : 0;     // right-neighbor valid
    const float fm = (float)dm, fp = (float)dp;

    float p[64];
    #pragma unroll
    for (int i = 0; i < 64; ++i) p[i] = 0.0f;

    #pragma unroll
    for (int dy = -1; dy <= 1; ++dy) {
        int yy = y + dy;
        if (yy >= 0 && yy < HH) {              // wave-uniform
            const int rb = (b << 14) + (yy << 7) + wcol;
            const float mp_m = (float)mpre[rb - dm];
            const float mp_0 = (float)mpre[rb];
            const float mp_p = (float)mpre[rb + dp];
            #pragma unroll
            for (int c = 0; c < CC; ++c) {
                const int gi  = ((b * CC + c) << 14) + (yy << 7) + wcol;
                const int gim = gi - dm;
                const int gip = gi + dp;
                float vm = __builtin_fmaf(goal[gim], mp_m, x[gim]) * fm;
                float v  = __builtin_fmaf(goal[gi ], mp_0, x[gi ]);
                float vp = __builtin_fmaf(goal[gip], mp_p, x[gip]) * fp;
                #pragma unroll
                for (int kk = 0; kk < 3; ++kk) {
                    const int t = 3 * c + kk;
                    const float* pr = pw + t * 9 + (dy + 1) * 3;
                    p[t] = __builtin_fmaf(pr[0], vm, p[t]);
                    p[t] = __builtin_fmaf(pr[1], v,  p[t]);
                    p[t] = __builtin_fmaf(pr[2], vp, p[t]);
                }
            }
        }
    }

    const int l15 = lane & 15;
    const int l4  = lane >> 4;

    // per-lane fp32 constants from GLOBAL (exactness for mask path)
    float bias_[8], w2r3[8];
    #pragma unroll
    for (int nt = 0; nt < 8; ++nt) {
        bias_[nt] = b1[nt * 16 + l15];
        w2r3[nt]  = w2[3 * 128 + nt * 16 + l15];
    }
    // GEMM2 B-frags: one-time coalesced loads from prep output
    short8 b2f[2][4];
    #pragma unroll
    for (int nt = 0; nt < 2; ++nt)
        #pragma unroll
        for (int ks = 0; ks < 4; ++ks)
            b2f[nt][ks] = *reinterpret_cast<const short8*>(
                w2f + (ks * 2 + nt) * 512 + lane * 8);

    float*          pbuf = &ph_buf[wv][0];                          // [16][68] f32
    unsigned short* hbuf = reinterpret_cast<unsigned short*>(pbuf); // [16][136] bf16

    const int hwbase = ((blk & 31) << 9) + (wv << 6);

    for (int mt = 0; mt < 4; ++mt) {
        // WAR: previous iteration's h reads (a2) precede this tile's p writes.
        LDS_FENCE();
        // ---- stage this tile's p rows fp32 (wave-local: lanes l4==mt own them) ----
        if (l4 == mt) {
            #pragma unroll
            for (int g = 0; g < 16; ++g) {
                f32x4 t = { p[g*4+0], p[g*4+1], p[g*4+2], p[g*4+3] };
                *reinterpret_cast<f32x4*>(pbuf + l15 * 68 + g * 4) = t;
            }
        }
        LDS_FENCE();

        // ---- PREFETCH epilogue operands (covered by GEMM1+GEMM2 MFMA latency) ----
        const int hw = hwbase + (mt << 4) + (l4 << 2);
        float4 r4 = *reinterpret_cast<const float4*>(rnd + (b << 14) + hw);
        float4 xo[2];
        #pragma unroll
        for (int nt = 0; nt < 2; ++nt) {
            int o = (nt << 4) + l15;
            if (o < CC)
                xo[nt] = *reinterpret_cast<const float4*>(x + (((b * CC + o) << 14) + hw));
        }

        // ---- A fragments: read fp32, split hi/lo in-register ----
        short8 ah[2], al[2];
        #pragma unroll
        for (int ks = 0; ks < 2; ++ks) {
            f32x4 u0 = *reinterpret_cast<const f32x4*>(pbuf + l15 * 68 + ks * 32 + l4 * 8);
            f32x4 u1 = *reinterpret_cast<const f32x4*>(pbuf + l15 * 68 + ks * 32 + l4 * 8 + 4);
            #pragma unroll
            for (int j = 0; j < 4; ++j) {
                unsigned short h0 = f2bf(u0[j]);
                ah[ks][j]     = (short)h0;
                al[ks][j]     = (short)f2bf(u0[j] - bf2f(h0));
                unsigned short h1 = f2bf(u1[j]);
                ah[ks][4 + j] = (short)h1;
                al[ks][4 + j] = (short)f2bf(u1[j] - bf2f(h1));
            }
        }

        // ---- GEMM1, 3-term split (al*bl < 2^-16 rel: dropped) ----
        f32x4 C1[8];
        #pragma unroll
        for (int nt = 0; nt < 8; ++nt) {
            f32x4 c = { bias_[nt], bias_[nt], bias_[nt], bias_[nt] };
            #pragma unroll
            for (int ks = 0; ks < 2; ++ks) {
                const int n = nt * 16 + l15;
                const int chunk = (((ks << 2) + l4) ^ (n & 7)) << 3;
                const short8 bh = *reinterpret_cast<const short8*>(w1h + (n << 6) + chunk);
                const short8 bl = *reinterpret_cast<const short8*>(w1l + (n << 6) + chunk);
                c = __builtin_amdgcn_mfma_f32_16x16x32_bf16(ah[ks], bh, c, 0, 0, 0);
                c = __builtin_amdgcn_mfma_f32_16x16x32_bf16(al[ks], bh, c, 0, 0, 0);
                c = __builtin_amdgcn_mfma_f32_16x16x32_bf16(ah[ks], bl, c, 0, 0, 0);
            }
            C1[nt] = c;
        }

        // ---- relu; ch3 partial in fp32 (mask-exact); stage h bf16 (overlays p tile) ----
        float s[4] = {0.f, 0.f, 0.f, 0.f};
        #pragma unroll
        for (int nt = 0; nt < 8; ++nt) {
            #pragma unroll
            for (int r = 0; r < 4; ++r) {
                float hv = fmaxf(C1[nt][r], 0.0f);
                s[r] = __builtin_fmaf(w2r3[nt], hv, s[r]);
                int hrow = (l4 << 2) + r;
                hbuf[hrow * 136 + ((nt * 16 + l15) ^ ((hrow & 7) << 3))] = f2bf(hv);
            }
        }
        LDS_FENCE();   // RAW: a2 reads below consume other lanes' h writes above

        // ---- GEMM2 single-bf16 (values only; ch3 overridden below) ----
        f32x4 C2[2];
        C2[0] = (f32x4){0.f, 0.f, 0.f, 0.f};
        C2[1] = (f32x4){0.f, 0.f, 0.f, 0.f};
        #pragma unroll
        for (int ks2 = 0; ks2 < 4; ++ks2) {
            int col0 = (ks2 * 32 + l4 * 8) ^ ((l15 & 7) << 3);
            short8 a2 = *reinterpret_cast<const short8*>(hbuf + l15 * 136 + col0);
            C2[0] = __builtin_amdgcn_mfma_f32_16x16x32_bf16(a2, b2f[0][ks2], C2[0], 0, 0, 0);
            C2[1] = __builtin_amdgcn_mfma_f32_16x16x32_bf16(a2, b2f[1][ks2], C2[1], 0, 0, 0);
        }

        // ---- reduce s over the 16-lane l15 group (after GEMM2: MFMA covers latency) ----
        #pragma unroll
        for (int r = 0; r < 4; ++r) {
            s[r] += __shfl_xor(s[r], 1, 64);
            s[r] += __shfl_xor(s[r], 2, 64);
            s[r] += __shfl_xor(s[r], 4, 64);
            s[r] += __shfl_xor(s[r], 8, 64);
        }

        // ---- epilogue: x_new = x + rand_mask * out (operands prefetched) ----
        float rm0 = (r4.x < 0.5f) ? 1.0f : 0.0f;
        float rm1 = (r4.y < 0.5f) ? 1.0f : 0.0f;
        float rm2 = (r4.z < 0.5f) ? 1.0f : 0.0f;
        float rm3 = (r4.w < 0.5f) ? 1.0f : 0.0f;
        #pragma unroll
        for (int nt = 0; nt < 2; ++nt) {
            int o = (nt << 4) + l15;
            if (o < CC) {
                const bool isliv = (nt == 0) && (l15 == LIVCH);
                float u0 = isliv ? s[0] : C2[nt][0];
                float u1 = isliv ? s[1] : C2[nt][1];
                float u2 = isliv ? s[2] : C2[nt][2];
                float u3 = isliv ? s[3] : C2[nt][3];
                int gi = ((b * CC + o) << 14) + hw;
                float4 vo;
                vo.x = __builtin_fmaf(rm0, u0, xo[nt].x);
                vo.y = __builtin_fmaf(rm1, u1, xo[nt].y);
                vo.z = __builtin_fmaf(rm2, u2, xo[nt].z);
                vo.w = __builtin_fmaf(rm3, u3, xo[nt].w);
                *reinterpret_cast<float4*>(xnew + gi) = vo;
                if (isliv)
                    *reinterpret_cast<float4*>(ch3out + (b << 14) + hw) = vo;
            }
        }
    }
}

// ---- Pass 3: post-alive + life mask + clip, 4 px/thread ----
__global__ __launch_bounds__(256) void nca_finalize(const float* __restrict__ ch3,
                                                    const unsigned char* __restrict__ mpre,
                                                    float* __restrict__ xnew) {
    int t = blockIdx.x * 256 + threadIdx.x;   // NPIX/4 threads
    int base = t << 2;
    int w4 = base & 127;
    int h  = (base >> 7) & 127;
    int b  = base >> 14;
    const float* plane = ch3 + b * (HH * WW);
    float4 L = {-1e30f, -1e30f, -1e30f, -1e30f};
    float4 Cn = L, R = L;
    #pragma unroll
    for (int dy = -1; dy <= 1; ++dy) {
        int yy = h + dy;
        if ((unsigned)yy < HH) {
            const float* row = plane + yy * WW;
            float4 c4 = *reinterpret_cast<const float4*>(row + w4);
            Cn.x = fmaxf(Cn.x, c4.x); Cn.y = fmaxf(Cn.y, c4.y);
            Cn.z = fmaxf(Cn.z, c4.z); Cn.w = fmaxf(Cn.w, c4.w);
            if (w4 > 0) {
                float4 l4 = *reinterpret_cast<const float4*>(row + w4 - 4);
                L.w = fmaxf(L.w, l4.w);
            }
            if (w4 < 124) {
                float4 r4 = *reinterpret_cast<const float4*>(row + w4 + 4);
                R.x = fmaxf(R.x, r4.x);
            }
        }
    }
    float m0 = fmaxf(fmaxf(L.w,  Cn.x), Cn.y);
    float m1 = fmaxf(fmaxf(Cn.x, Cn.y), Cn.z);
    float m2 = fmaxf(fmaxf(Cn.y, Cn.z), Cn.w);
    float m3 = fmaxf(fmaxf(Cn.z, Cn.w), R.x);
    unsigned int pre4 = reinterpret_cast<const unsigned int*>(mpre)[t];
    float life0 = ((pre4 & 0x000000ffu) && m0 > 0.1f) ? 1.0f : 0.0f;
    float life1 = ((pre4 & 0x0000ff00u) && m1 > 0.1f) ? 1.0f : 0.0f;
    float life2 = ((pre4 & 0x00ff0000u) && m2 > 0.1f) ? 1.0f : 0.0f;
    float life3 = ((pre4 & 0xff000000u) && m3 > 0.1f) ? 1.0f : 0.0f;

    int pix = (h << 7) + w4;
    #pragma unroll
    for (int c = 0; c < CC; ++c) {
        int gi = ((b * CC + c) << 14) + pix;
        float4 v = *reinterpret_cast<const float4*>(xnew + gi);
        v.x = fminf(fmaxf(v.x * life0, -10.0f), 10.0f);
        v.y = fminf(fmaxf(v.y * life1, -10.0f), 10.0f);
        v.z = fminf(fmaxf(v.z * life2, -10.0f), 10.0f);
        v.w = fminf(fmaxf(v.w * life3, -10.0f), 10.0f);
        *reinterpret_cast<float4*>(xnew + gi) = v;
    }
}

extern "C" void kernel_launch(void* const* d_in, const int* in_sizes, int n_in,
                              void* d_out, int out_size, void* d_ws, size_t ws_size,
                              hipStream_t stream) {
    const float* x    = (const float*)d_in[0];
    const float* goal = (const float*)d_in[1];
    const float* rnd  = (const float*)d_in[2];
    const float* pw   = (const float*)d_in[3];
    const float* w1   = (const float*)d_in[4];
    const float* b1   = (const float*)d_in[5];
    const float* w2   = (const float*)d_in[6];
    float* out = (float*)d_out;

    // ws layout: [0,1MB) mpre u8; [1MB,5MB) ch3 f32; [5MB,+8KB) w2f bf16 frags.
    unsigned char*  mpre = (unsigned char*)d_ws;
    float*          ch3  = (float*)((char*)d_ws + NPIX);
    unsigned short* w2f  = (unsigned short*)((char*)d_ws + NPIX + (size_t)NPIX * 4);

    dim3 blk(256);
    hipLaunchKernelGGL(nca_pre_mask, dim3(NPIX / 1024), blk, 0, stream, x, mpre, w2, w2f);
    hipLaunchKernelGGL(nca_main_mfma, dim3(NPIX / 512), dim3(512), 0, stream,
                       x, goal, rnd, pw, w1, b1, w2f, w2, mpre, out, ch3);
    hipLaunchKernelGGL(nca_finalize, dim3(NPIX / 1024), blk, 0, stream, ch3, mpre, out);
}

// Round 19
// 244.148 us; speedup vs baseline: 1.1369x; 1.1369x over previous
//
#include <hip/hip_runtime.h>
#include <hip/hip_bf16.h>

// ControllableNCA step. B=64, C=20, H=W=128. LIVING=3, ALIVE_TH=0.1, FIRE_RATE=0.5.
// Pass 1: pre-alive mask (u8, 4 px/thread) + inline w2->bf16 frag prep (threads 0-511).
// Pass 2: conv(fp32, offset-load neighbors) -> GEMM1 3-term split-bf16
//         (fp32-grade h; w1 hi/lo swizzled LDS) -> ch3 update fp32 on VALU
//         (mask channel: threshold discontinuity) -> GEMM2 single-bf16 ->
//         stochastic update. XCD-swizzled grid. NO epilogue prefetch
//         (R18: holding r4/xo across GEMM spilled, WRITE 86->171MB).
// Pass 3: post-alive + life mask + clip, 4 px/thread float4.
// R19: R16 chassis verbatim (best verified, 250us) + prep merge only.

#define BB 64
#define CC 20
#define HH 128
#define WW 128
#define LIVCH 3
#define NPIX (BB*HH*WW)

typedef __attribute__((ext_vector_type(8))) short short8;
typedef __attribute__((ext_vector_type(4))) float f32x4;

#define LDS_FENCE() asm volatile("" ::: "memory")

static __device__ __forceinline__ unsigned short f2bf(float f) {
    __hip_bfloat16 h = __float2bfloat16(f);   // RNE
    return *reinterpret_cast<unsigned short*>(&h);
}
static __device__ __forceinline__ float bf2f(unsigned short u) {
    union { unsigned int i; float f; } c; c.i = ((unsigned int)u) << 16; return c.f;
}

// ---- Pass 1: pre-alive mask, 4 px/thread; threads 0-511 also convert w2->w2f ----
__global__ __launch_bounds__(256) void nca_pre_mask(const float* __restrict__ x,
                                                    unsigned char* __restrict__ mpre,
                                                    const float* __restrict__ w2,
                                                    unsigned short* __restrict__ w2f) {
    int t = blockIdx.x * 256 + threadIdx.x;   // NPIX/4 threads
    // inline prep: w2f = 8 frags (ks2*2 + nt2) x 64 lanes x 8 bf16 (n>=20 zero)
    if (t < 512) {
        int f2 = t >> 6, lane = t & 63;
        int ks2 = f2 >> 1, nt2 = f2 & 1;
        int n = nt2 * 16 + (lane & 15), kb = ks2 * 32 + (lane >> 4) * 8;
        short8 o;
        #pragma unroll
        for (int j = 0; j < 8; ++j) {
            float v = (n < CC) ? w2[n * 128 + kb + j] : 0.0f;
            o[j] = (short)f2bf(v);
        }
        *reinterpret_cast<short8*>(w2f + f2 * 512 + lane * 8) = o;
    }
    int base = t << 2;
    int w4 = base & 127;
    int h  = (base >> 7) & 127;
    int b  = base >> 14;
    const float* ch = x + ((size_t)b * CC + LIVCH) * (HH * WW);
    float4 L = {-1e30f, -1e30f, -1e30f, -1e30f};
    float4 Cn = L, R = L;
    #pragma unroll
    for (int dy = -1; dy <= 1; ++dy) {
        int yy = h + dy;
        if ((unsigned)yy < HH) {
            const float* row = ch + yy * WW;
            float4 c4 = *reinterpret_cast<const float4*>(row + w4);
            Cn.x = fmaxf(Cn.x, c4.x); Cn.y = fmaxf(Cn.y, c4.y);
            Cn.z = fmaxf(Cn.z, c4.z); Cn.w = fmaxf(Cn.w, c4.w);
            if (w4 > 0) {
                float4 l4 = *reinterpret_cast<const float4*>(row + w4 - 4);
                L.w = fmaxf(L.w, l4.w);
            }
            if (w4 < 124) {
                float4 r4 = *reinterpret_cast<const float4*>(row + w4 + 4);
                R.x = fmaxf(R.x, r4.x);
            }
        }
    }
    float m0 = fmaxf(fmaxf(L.w,  Cn.x), Cn.y);
    float m1 = fmaxf(fmaxf(Cn.x, Cn.y), Cn.z);
    float m2 = fmaxf(fmaxf(Cn.y, Cn.z), Cn.w);
    float m3 = fmaxf(fmaxf(Cn.z, Cn.w), R.x);
    unsigned int out = (m0 > 0.1f ? 1u : 0u) | (m1 > 0.1f ? 1u << 8 : 0u)
                     | (m2 > 0.1f ? 1u << 16 : 0u) | (m3 > 0.1f ? 1u << 24 : 0u);
    reinterpret_cast<unsigned int*>(mpre)[t] = out;
}

// Block: 512 threads = 8 waves; 512 pixels = 4 image rows. Grid = 64*32 = 2048.
__global__ __launch_bounds__(512, 2) void nca_main_mfma(
    const float* __restrict__ x, const float* __restrict__ goal,
    const float* __restrict__ rnd, const float* __restrict__ pw,
    const float* __restrict__ w1, const float* __restrict__ b1,
    const unsigned short* __restrict__ w2f, const float* __restrict__ w2,
    const unsigned char* __restrict__ mpre,
    float* __restrict__ xnew, float* __restrict__ ch3out) {

    // w1 hi/lo: [128][64] bf16, UNPADDED, 16B-chunk XOR swizzle:
    //   elem (n,k) at short index n*64 + (((k>>3)^(n&7))<<3) + (k&7)
    __shared__ unsigned short w1h[128 * 64];   // 16384 B
    __shared__ unsigned short w1l[128 * 64];   // 16384 B
    // per-wave shared tile: p view [16][68] f32, h view [16][136] bf16
    __shared__ float ph_buf[8][16 * 68];       // 34816 B
    // total 67584 B -> 2 blocks/CU

    const int tid  = threadIdx.x;
    const int lane = tid & 63;
    const int wv   = tid >> 6;                 // 0..7
    // bijective XCD swizzle (nwg=2048, 8 XCDs): each XCD gets 256 contiguous
    // row-tiles -> halo rows + mpre reuse stay in one L2.
    const int bid  = blockIdx.x;
    const int blk  = ((bid & 7) << 8) + (bid >> 3);
    const int b    = blk >> 5;                 // 32 blocks per image
    const int y0   = (blk & 31) * 4;           // 4 rows per block

    // ---- stage w1 hi/lo split (Dekker: v = hi + lo + O(2^-17 v)), swizzled ----
    for (int i = tid; i < 128 * 64; i += 512) {
        int n = i >> 6, k = i & 63;
        float v = (k < 60) ? w1[n * 60 + k] : 0.0f;
        unsigned short hi = f2bf(v);
        int si = (n << 6) + ((((k >> 3) ^ (n & 7)) << 3)) + (k & 7);
        w1h[si] = hi;
        w1l[si] = f2bf(v - bf2f(hi));
    }
    __syncthreads();   // w1 staging visible to all waves

    // ---- depthwise 3x3 conv on xg, per-lane pixel, fp32, offset-load neighbors ----
    const int y    = y0 + (tid >> 7);          // tid>>7 in 0..3
    const int wcol = tid & 127;
    const int dm   = (wcol > 0)   ? 1 : 0;     // left-neighbor valid
    const int dp   = (wcol < 127) ? 1 : 0;     // right-neighbor valid
    const float fm = (float)dm, fp = (float)dp;

    float p[64];
    #pragma unroll
    for (int i = 0; i < 64; ++i) p[i] = 0.0f;

    #pragma unroll
    for (int dy = -1; dy <= 1; ++dy) {
        int yy = y + dy;
        if (yy >= 0 && yy < HH) {              // wave-uniform
            const int rb = (b << 14) + (yy << 7) + wcol;
            const float mp_m = (float)mpre[rb - dm];
            const float mp_0 = (float)mpre[rb];
            const float mp_p = (float)mpre[rb + dp];
            #pragma unroll
            for (int c = 0; c < CC; ++c) {
                const int gi  = ((b * CC + c) << 14) + (yy << 7) + wcol;
                const int gim = gi - dm;
                const int gip = gi + dp;
                float vm = __builtin_fmaf(goal[gim], mp_m, x[gim]) * fm;
                float v  = __builtin_fmaf(goal[gi ], mp_0, x[gi ]);
                float vp = __builtin_fmaf(goal[gip], mp_p, x[gip]) * fp;
                #pragma unroll
                for (int kk = 0; kk < 3; ++kk) {
                    const int t = 3 * c + kk;
                    const float* pr = pw + t * 9 + (dy + 1) * 3;
                    p[t] = __builtin_fmaf(pr[0], vm, p[t]);
                    p[t] = __builtin_fmaf(pr[1], v,  p[t]);
                    p[t] = __builtin_fmaf(pr[2], vp, p[t]);
                }
            }
        }
    }

    const int l15 = lane & 15;
    const int l4  = lane >> 4;

    // per-lane fp32 constants from GLOBAL (exactness for mask path)
    float bias_[8], w2r3[8];
    #pragma unroll
    for (int nt = 0; nt < 8; ++nt) {
        bias_[nt] = b1[nt * 16 + l15];
        w2r3[nt]  = w2[3 * 128 + nt * 16 + l15];
    }
    // GEMM2 B-frags: one-time coalesced loads from prep output
    short8 b2f[2][4];
    #pragma unroll
    for (int nt = 0; nt < 2; ++nt)
        #pragma unroll
        for (int ks = 0; ks < 4; ++ks)
            b2f[nt][ks] = *reinterpret_cast<const short8*>(
                w2f + (ks * 2 + nt) * 512 + lane * 8);

    float*          pbuf = &ph_buf[wv][0];                          // [16][68] f32
    unsigned short* hbuf = reinterpret_cast<unsigned short*>(pbuf); // [16][136] bf16

    const int hwbase = ((blk & 31) << 9) + (wv << 6);

    for (int mt = 0; mt < 4; ++mt) {
        // WAR: previous iteration's h reads (a2) precede this tile's p writes.
        LDS_FENCE();
        // ---- stage this tile's p rows fp32 (wave-local: lanes l4==mt own them) ----
        if (l4 == mt) {
            #pragma unroll
            for (int g = 0; g < 16; ++g) {
                f32x4 t = { p[g*4+0], p[g*4+1], p[g*4+2], p[g*4+3] };
                *reinterpret_cast<f32x4*>(pbuf + l15 * 68 + g * 4) = t;
            }
        }
        LDS_FENCE();

        // ---- A fragments: read fp32, split hi/lo in-register ----
        short8 ah[2], al[2];
        #pragma unroll
        for (int ks = 0; ks < 2; ++ks) {
            f32x4 u0 = *reinterpret_cast<const f32x4*>(pbuf + l15 * 68 + ks * 32 + l4 * 8);
            f32x4 u1 = *reinterpret_cast<const f32x4*>(pbuf + l15 * 68 + ks * 32 + l4 * 8 + 4);
            #pragma unroll
            for (int j = 0; j < 4; ++j) {
                unsigned short h0 = f2bf(u0[j]);
                ah[ks][j]     = (short)h0;
                al[ks][j]     = (short)f2bf(u0[j] - bf2f(h0));
                unsigned short h1 = f2bf(u1[j]);
                ah[ks][4 + j] = (short)h1;
                al[ks][4 + j] = (short)f2bf(u1[j] - bf2f(h1));
            }
        }

        // ---- GEMM1, 3-term split (al*bl < 2^-16 rel: dropped) ----
        f32x4 C1[8];
        #pragma unroll
        for (int nt = 0; nt < 8; ++nt) {
            f32x4 c = { bias_[nt], bias_[nt], bias_[nt], bias_[nt] };
            #pragma unroll
            for (int ks = 0; ks < 2; ++ks) {
                const int n = nt * 16 + l15;
                const int chunk = (((ks << 2) + l4) ^ (n & 7)) << 3;
                const short8 bh = *reinterpret_cast<const short8*>(w1h + (n << 6) + chunk);
                const short8 bl = *reinterpret_cast<const short8*>(w1l + (n << 6) + chunk);
                c = __builtin_amdgcn_mfma_f32_16x16x32_bf16(ah[ks], bh, c, 0, 0, 0);
                c = __builtin_amdgcn_mfma_f32_16x16x32_bf16(al[ks], bh, c, 0, 0, 0);
                c = __builtin_amdgcn_mfma_f32_16x16x32_bf16(ah[ks], bl, c, 0, 0, 0);
            }
            C1[nt] = c;
        }

        // ---- relu; ch3 partial in fp32 (mask-exact); stage h bf16 (overlays p tile) ----
        float s[4] = {0.f, 0.f, 0.f, 0.f};
        #pragma unroll
        for (int nt = 0; nt < 8; ++nt) {
            #pragma unroll
            for (int r = 0; r < 4; ++r) {
                float hv = fmaxf(C1[nt][r], 0.0f);
                s[r] = __builtin_fmaf(w2r3[nt], hv, s[r]);
                int hrow = (l4 << 2) + r;
                hbuf[hrow * 136 + ((nt * 16 + l15) ^ ((hrow & 7) << 3))] = f2bf(hv);
            }
        }
        LDS_FENCE();   // RAW: a2 reads below consume other lanes' h writes above

        // ---- GEMM2 single-bf16 (values only; ch3 overridden below) ----
        f32x4 C2[2];
        C2[0] = (f32x4){0.f, 0.f, 0.f, 0.f};
        C2[1] = (f32x4){0.f, 0.f, 0.f, 0.f};
        #pragma unroll
        for (int ks2 = 0; ks2 < 4; ++ks2) {
            int col0 = (ks2 * 32 + l4 * 8) ^ ((l15 & 7) << 3);
            short8 a2 = *reinterpret_cast<const short8*>(hbuf + l15 * 136 + col0);
            C2[0] = __builtin_amdgcn_mfma_f32_16x16x32_bf16(a2, b2f[0][ks2], C2[0], 0, 0, 0);
            C2[1] = __builtin_amdgcn_mfma_f32_16x16x32_bf16(a2, b2f[1][ks2], C2[1], 0, 0, 0);
        }

        // ---- reduce s over the 16-lane l15 group (after GEMM2: MFMA covers latency) ----
        #pragma unroll
        for (int r = 0; r < 4; ++r) {
            s[r] += __shfl_xor(s[r], 1, 64);
            s[r] += __shfl_xor(s[r], 2, 64);
            s[r] += __shfl_xor(s[r], 4, 64);
            s[r] += __shfl_xor(s[r], 8, 64);
        }

        // ---- epilogue: x_new = x + rand_mask * out ----
        const int hw = hwbase + (mt << 4) + (l4 << 2);
        float4 r4 = *reinterpret_cast<const float4*>(rnd + (b << 14) + hw);
        float rm0 = (r4.x < 0.5f) ? 1.0f : 0.0f;
        float rm1 = (r4.y < 0.5f) ? 1.0f : 0.0f;
        float rm2 = (r4.z < 0.5f) ? 1.0f : 0.0f;
        float rm3 = (r4.w < 0.5f) ? 1.0f : 0.0f;
        #pragma unroll
        for (int nt = 0; nt < 2; ++nt) {
            int o = (nt << 4) + l15;
            if (o < CC) {
                const bool isliv = (nt == 0) && (l15 == LIVCH);
                float u0 = isliv ? s[0] : C2[nt][0];
                float u1 = isliv ? s[1] : C2[nt][1];
                float u2 = isliv ? s[2] : C2[nt][2];
                float u3 = isliv ? s[3] : C2[nt][3];
                int gi = ((b * CC + o) << 14) + hw;
                float4 xo = *reinterpret_cast<const float4*>(x + gi);
                float4 vo;
                vo.x = __builtin_fmaf(rm0, u0, xo.x);
                vo.y = __builtin_fmaf(rm1, u1, xo.y);
                vo.z = __builtin_fmaf(rm2, u2, xo.z);
                vo.w = __builtin_fmaf(rm3, u3, xo.w);
                *reinterpret_cast<float4*>(xnew + gi) = vo;
                if (isliv)
                    *reinterpret_cast<float4*>(ch3out + (b << 14) + hw) = vo;
            }
        }
    }
}

// ---- Pass 3: post-alive + life mask + clip, 4 px/thread ----
__global__ __launch_bounds__(256) void nca_finalize(const float* __restrict__ ch3,
                                                    const unsigned char* __restrict__ mpre,
                                                    float* __restrict__ xnew) {
    int t = blockIdx.x * 256 + threadIdx.x;   // NPIX/4 threads
    int base = t << 2;
    int w4 = base & 127;
    int h  = (base >> 7) & 127;
    int b  = base >> 14;
    const float* plane = ch3 + b * (HH * WW);
    float4 L = {-1e30f, -1e30f, -1e30f, -1e30f};
    float4 Cn = L, R = L;
    #pragma unroll
    for (int dy = -1; dy <= 1; ++dy) {
        int yy = h + dy;
        if ((unsigned)yy < HH) {
            const float* row = plane + yy * WW;
            float4 c4 = *reinterpret_cast<const float4*>(row + w4);
            Cn.x = fmaxf(Cn.x, c4.x); Cn.y = fmaxf(Cn.y, c4.y);
            Cn.z = fmaxf(Cn.z, c4.z); Cn.w = fmaxf(Cn.w, c4.w);
            if (w4 > 0) {
                float4 l4 = *reinterpret_cast<const float4*>(row + w4 - 4);
                L.w = fmaxf(L.w, l4.w);
            }
            if (w4 < 124) {
                float4 r4 = *reinterpret_cast<const float4*>(row + w4 + 4);
                R.x = fmaxf(R.x, r4.x);
            }
        }
    }
    float m0 = fmaxf(fmaxf(L.w,  Cn.x), Cn.y);
    float m1 = fmaxf(fmaxf(Cn.x, Cn.y), Cn.z);
    float m2 = fmaxf(fmaxf(Cn.y, Cn.z), Cn.w);
    float m3 = fmaxf(fmaxf(Cn.z, Cn.w), R.x);
    unsigned int pre4 = reinterpret_cast<const unsigned int*>(mpre)[t];
    float life0 = ((pre4 & 0x000000ffu) && m0 > 0.1f) ? 1.0f : 0.0f;
    float life1 = ((pre4 & 0x0000ff00u) && m1 > 0.1f) ? 1.0f : 0.0f;
    float life2 = ((pre4 & 0x00ff0000u) && m2 > 0.1f) ? 1.0f : 0.0f;
    float life3 = ((pre4 & 0xff000000u) && m3 > 0.1f) ? 1.0f : 0.0f;

    int pix = (h << 7) + w4;
    #pragma unroll
    for (int c = 0; c < CC; ++c) {
        int gi = ((b * CC + c) << 14) + pix;
        float4 v = *reinterpret_cast<const float4*>(xnew + gi);
        v.x = fminf(fmaxf(v.x * life0, -10.0f), 10.0f);
        v.y = fminf(fmaxf(v.y * life1, -10.0f), 10.0f);
        v.z = fminf(fmaxf(v.z * life2, -10.0f), 10.0f);
        v.w = fminf(fmaxf(v.w * life3, -10.0f), 10.0f);
        *reinterpret_cast<float4*>(xnew + gi) = v;
    }
}

extern "C" void kernel_launch(void* const* d_in, const int* in_sizes, int n_in,
                              void* d_out, int out_size, void* d_ws, size_t ws_size,
                              hipStream_t stream) {
    const float* x    = (const float*)d_in[0];
    const float* goal = (const float*)d_in[1];
    const float* rnd  = (const float*)d_in[2];
    const float* pw   = (const float*)d_in[3];
    const float* w1   = (const float*)d_in[4];
    const float* b1   = (const float*)d_in[5];
    const float* w2   = (const float*)d_in[6];
    float* out = (float*)d_out;

    // ws layout: [0,1MB) mpre u8; [1MB,5MB) ch3 f32; [5MB,+8KB) w2f bf16 frags.
    unsigned char*  mpre = (unsigned char*)d_ws;
    float*          ch3  = (float*)((char*)d_ws + NPIX);
    unsigned short* w2f  = (unsigned short*)((char*)d_ws + NPIX + (size_t)NPIX * 4);

    dim3 blk(256);
    hipLaunchKernelGGL(nca_pre_mask, dim3(NPIX / 1024), blk, 0, stream, x, mpre, w2, w2f);
    hipLaunchKernelGGL(nca_main_mfma, dim3(NPIX / 512), dim3(512), 0, stream,
                       x, goal, rnd, pw, w1, b1, w2f, w2, mpre, out, ch3);
    hipLaunchKernelGGL(nca_finalize, dim3(NPIX / 1024), blk, 0, stream, ch3, mpre, out);
}